// Round 3
// baseline (402.183 us; speedup 1.0000x reference)
//
#include <hip/hip_runtime.h>
#include <hip/hip_fp16.h>

#define N_AGENTS 8192
#define FDIM 128
#define PDIM 16
#define NEDGES 262144

#define EDGE_BLOCKS 512           // fused kernel: blocks [0, EDGE_BLOCKS) do edge dots
#define ZERO_BLOCKS 1536          // fused kernel: blocks [EDGE_BLOCKS, ...) zero out
#define OUT4 ((size_t)N_AGENTS * N_AGENTS / 4)

typedef float floatx4 __attribute__((ext_vector_type(4)));   // native vec for nontemporal

// ------------------------------------------------- per-row precompute (1 wave/row)
// T[row][0:128)  = fp16 row-L2-normalized next_feature
// T[row][128:256)= fp16 (feature - next_feature)
// scale[row] = (persona.alpha, persona.gamma / F)   brow[row] = persona.beta
__global__ __launch_bounds__(256) void row_prep_k(
        const float* __restrict__ feature,
        const float* __restrict__ next_feature,
        const float* __restrict__ persona,
        const float* __restrict__ alpha,
        const float* __restrict__ beta,
        const float* __restrict__ gamma,
        __half2* __restrict__ T2,          // N * 128 half2 per row
        float2* __restrict__ scale,
        float* __restrict__ brow) {
    int row  = (blockIdx.x * blockDim.x + threadIdx.x) >> 6;   // one wave64 per row
    int lane = threadIdx.x & 63;
    if (row >= N_AGENTS) return;

    const float2* f2 = (const float2*)(feature      + (size_t)row * FDIM);
    const float2* n2 = (const float2*)(next_feature + (size_t)row * FDIM);
    float2 f  = f2[lane];          // 64 lanes x float2 = 128 floats
    float2 nx = n2[lane];

    float2 d = make_float2(f.x - nx.x, f.y - nx.y);
    float ss = nx.x * nx.x + nx.y * nx.y;

    float pa = 0.f, pb = 0.f, pg = 0.f;
    if (lane < PDIM) {
        float p = persona[(size_t)row * PDIM + lane];
        pa = p * alpha[lane];
        pb = p * beta[lane];
        pg = p * gamma[lane];
    }

    #pragma unroll
    for (int off = 32; off > 0; off >>= 1) {
        ss += __shfl_xor(ss, off);
        pa += __shfl_xor(pa, off);
        pb += __shfl_xor(pb, off);
        pg += __shfl_xor(pg, off);
    }

    float inv = 1.0f / sqrtf(ss);
    __half2* trow = T2 + (size_t)row * 128;
    trow[lane]      = __float22half2_rn(make_float2(nx.x * inv, nx.y * inv)); // nf
    trow[64 + lane] = __float22half2_rn(d);                                   // diff

    if (lane == 0) {
        scale[row] = make_float2(pa, pg * (1.0f / FDIM));
        brow[row]  = pb;
    }
}

// 8 halves (one float4-sized chunk) fp16 dot, fp32 accumulate
__device__ inline float dot8(float4 a, float4 b) {
    const __half2* ha = (const __half2*)&a;
    const __half2* hb = (const __half2*)&b;
    float s = 0.f;
    #pragma unroll
    for (int j = 0; j < 4; ++j) {
        float2 fa = __half22float2(ha[j]);
        float2 fb = __half22float2(hb[j]);
        s += fa.x * fb.x + fa.y * fb.y;
    }
    return s;
}

// ------------------------------------------------- fused: edge dots || zero fill
__global__ __launch_bounds__(256) void fused_k(
        const int* __restrict__ asrc,
        const int* __restrict__ adst,
        const __half* __restrict__ T,      // N x 256 halves
        const float2* __restrict__ scale,
        float* __restrict__ vals,
        floatx4* __restrict__ out4) {
    int b = blockIdx.x;
    if (b < EDGE_BLOCKS) {
        // --- act-edge dot products -> vals[e] (independent of the zero fill)
        int lane16 = threadIdx.x & 15;
        int e      = (b * 256 + (int)threadIdx.x) >> 4;
        const int estride = (EDGE_BLOCKS * 256) >> 4;   // 8192 edges per sweep
        for (; e < NEDGES; e += estride) {
            int s = asrc[e];
            int d = adst[e];
            const float4* ts = (const float4*)(T + (size_t)s * 256);
            const float4* td = (const float4*)(T + (size_t)d * 256);
            int i0 = lane16 * 2;        // lanes 0-7: f4 0..15 (sim) ; 8-15: 16..31 (imp)
            float acc = dot8(ts[i0], td[i0]) + dot8(ts[i0 + 1], td[i0 + 1]);
            acc += __shfl_xor(acc, 1, 16);
            acc += __shfl_xor(acc, 2, 16);
            acc += __shfl_xor(acc, 4, 16);        // lanes 0-7 = sim total, 8-15 = imp total
            float other = __shfl_xor(acc, 8, 16); // on lane 0: imp total
            if (lane16 == 0) {
                float2 sc = scale[s];
                vals[e] = acc * sc.x + other * sc.y;
            }
        }
    } else {
        // --- zero the 256 MiB output with nontemporal streaming stores
        int zb = b - EDGE_BLOCKS;
        size_t i = (size_t)zb * 256 + threadIdx.x;
        const size_t stride = (size_t)ZERO_BLOCKS * 256;
        floatx4 z = (floatx4)0.f;
        for (; i < OUT4; i += stride)
            __builtin_nontemporal_store(z, &out4[i]);
    }
}

// ------------------------------------------------- scatter: both edge lists, atomics
__global__ __launch_bounds__(256) void scatter_k(
        const int* __restrict__ asrc,
        const int* __restrict__ adst,
        const int* __restrict__ esrc,
        const int* __restrict__ edst,
        const float* __restrict__ vals,
        const float* __restrict__ brow,
        float* __restrict__ out) {
    int gid = blockIdx.x * blockDim.x + threadIdx.x;
    if (gid < NEDGES) {
        int s = asrc[gid];
        atomicAdd(out + (size_t)s * N_AGENTS + adst[gid], vals[gid]);
    } else {
        int e = gid - NEDGES;
        int s = esrc[e];
        atomicAdd(out + (size_t)s * N_AGENTS + edst[e], -brow[s]);
    }
}

// ---------------------------------------------------------------- launcher
extern "C" void kernel_launch(void* const* d_in, const int* in_sizes, int n_in,
                              void* d_out, int out_size, void* d_ws, size_t ws_size,
                              hipStream_t stream) {
    const float* feature      = (const float*)d_in[0];
    const float* next_feature = (const float*)d_in[1];
    const float* persona      = (const float*)d_in[2];
    const float* alpha        = (const float*)d_in[3];
    const float* beta         = (const float*)d_in[4];
    const float* gamma        = (const float*)d_in[5];
    const int*   act_src      = (const int*)d_in[6];
    const int*   act_dst      = (const int*)d_in[7];
    const int*   edge_src     = (const int*)d_in[8];
    const int*   edge_dst     = (const int*)d_in[9];

    float* out = (float*)d_out;

    // ws layout: T (N*256 half = 4 MiB) | scale (N float2) | brow (N float) | vals (E float)
    char* ws = (char*)d_ws;
    __half* T     = (__half*)ws;
    float2* scale = (float2*)(ws + (size_t)N_AGENTS * 256 * sizeof(__half));
    float*  brow  = (float*)((char*)scale + (size_t)N_AGENTS * sizeof(float2));
    float*  vals  = (float*)((char*)brow  + (size_t)N_AGENTS * sizeof(float));

    // 1) per-row precompute (fp16 table + persona scalars)
    row_prep_k<<<N_AGENTS / 4, 256, 0, stream>>>(
        feature, next_feature, persona, alpha, beta, gamma,
        (__half2*)T, scale, brow);

    // 2) fused: edge dot products (blocks 0..511) || zero-fill output (blocks 512..2047)
    fused_k<<<EDGE_BLOCKS + ZERO_BLOCKS, 256, 0, stream>>>(
        act_src, act_dst, T, scale, vals, (floatx4*)out);

    // 3) scatter both edge lists with atomics
    scatter_k<<<(2 * NEDGES) / 256, 256, 0, stream>>>(
        act_src, act_dst, edge_src, edge_dst, vals, brow, out);
}

// Round 4
// 338.976 us; speedup vs baseline: 1.1865x; 1.1865x over previous
//
#include <hip/hip_runtime.h>
#include <hip/hip_fp16.h>

#define N_AGENTS 8192
#define FDIM 128
#define PDIM 16
#define NEDGES 262144
#define CAP 256          // per-row bin capacity; degree ~ Poisson(64), tail << CAP
#define OVERCAP 4096     // safety overflow list

// ------------------------------------------------- per-row precompute (1 wave/row)
// T[row][0:128)  = fp16 row-L2-normalized next_feature
// T[row][128:256)= fp16 (feature - next_feature)
// scale[row] = (persona.alpha, persona.gamma/F)   brow[row] = persona.beta
// Also zeroes cnt[row] and (block 0) the overflow counter.
__global__ __launch_bounds__(256) void row_prep_k(
        const float* __restrict__ feature,
        const float* __restrict__ next_feature,
        const float* __restrict__ persona,
        const float* __restrict__ alpha,
        const float* __restrict__ beta,
        const float* __restrict__ gamma,
        __half2* __restrict__ T2,
        float2* __restrict__ scale,
        float* __restrict__ brow,
        int* __restrict__ cnt,
        int* __restrict__ ocnt) {
    int row  = (blockIdx.x * blockDim.x + threadIdx.x) >> 6;   // one wave64 per row
    int lane = threadIdx.x & 63;
    if (blockIdx.x == 0 && threadIdx.x == 0) *ocnt = 0;
    if (row >= N_AGENTS) return;

    const float2* f2 = (const float2*)(feature      + (size_t)row * FDIM);
    const float2* n2 = (const float2*)(next_feature + (size_t)row * FDIM);
    float2 f  = f2[lane];
    float2 nx = n2[lane];

    float2 d = make_float2(f.x - nx.x, f.y - nx.y);
    float ss = nx.x * nx.x + nx.y * nx.y;

    float pa = 0.f, pb = 0.f, pg = 0.f;
    if (lane < PDIM) {
        float p = persona[(size_t)row * PDIM + lane];
        pa = p * alpha[lane];
        pb = p * beta[lane];
        pg = p * gamma[lane];
    }

    #pragma unroll
    for (int off = 32; off > 0; off >>= 1) {
        ss += __shfl_xor(ss, off);
        pa += __shfl_xor(pa, off);
        pb += __shfl_xor(pb, off);
        pg += __shfl_xor(pg, off);
    }

    float inv = 1.0f / sqrtf(ss);
    __half2* trow = T2 + (size_t)row * 128;
    trow[lane]      = __float22half2_rn(make_float2(nx.x * inv, nx.y * inv)); // nf
    trow[64 + lane] = __float22half2_rn(d);                                   // diff

    if (lane == 0) {
        scale[row] = make_float2(pa, pg * (1.0f / FDIM));
        brow[row]  = pb;
        cnt[row]   = 0;
    }
}

// 8 halves (one float4 chunk) fp16 dot, fp32 accumulate
__device__ inline float dot8(float4 a, float4 b) {
    const __half2* ha = (const __half2*)&a;
    const __half2* hb = (const __half2*)&b;
    float s = 0.f;
    #pragma unroll
    for (int j = 0; j < 4; ++j) {
        float2 fa = __half22float2(ha[j]);
        float2 fb = __half22float2(hb[j]);
        s += fa.x * fb.x + fa.y * fb.y;
    }
    return s;
}

__device__ inline void push_rec(int s, int d, float val,
                                int* cnt, int2* bins,
                                int* ocnt, int4* olist) {
    int pos = atomicAdd(&cnt[s], 1);
    if (pos < CAP) {
        bins[(size_t)s * CAP + pos] = make_int2(d, __float_as_int(val));
    } else {
        int op = atomicAdd(ocnt, 1);
        if (op < OVERCAP) olist[op] = make_int4(s, d, __float_as_int(val), 0);
    }
}

// ------------------------------------------------- edge values -> binned records
// blocks [0, 16384): act edges, 16 lanes/edge (fp16 dots)
// blocks [16384, 17408): cost edges, 1 thread/edge
#define ACT_BLOCKS ((NEDGES * 16) / 256)
#define COST_BLOCKS (NEDGES / 256)
__global__ __launch_bounds__(256) void edge_bin_k(
        const int* __restrict__ asrc,
        const int* __restrict__ adst,
        const int* __restrict__ esrc,
        const int* __restrict__ edst,
        const __half* __restrict__ T,
        const float2* __restrict__ scale,
        const float* __restrict__ brow,
        int* __restrict__ cnt,
        int2* __restrict__ bins,
        int* __restrict__ ocnt,
        int4* __restrict__ olist) {
    int b = blockIdx.x;
    if (b < ACT_BLOCKS) {
        int gid    = b * 256 + threadIdx.x;
        int e      = gid >> 4;
        int lane16 = gid & 15;
        int s = asrc[e];
        int d = adst[e];
        const float4* ts = (const float4*)(T + (size_t)s * 256);
        const float4* td = (const float4*)(T + (size_t)d * 256);
        int i0 = lane16 * 2;          // lanes 0-7: nf chunks 0..15 ; lanes 8-15: diff 16..31
        float acc = dot8(ts[i0], td[i0]) + dot8(ts[i0 + 1], td[i0 + 1]);
        acc += __shfl_xor(acc, 1, 16);
        acc += __shfl_xor(acc, 2, 16);
        acc += __shfl_xor(acc, 4, 16);        // lanes 0-7 = sim, 8-15 = imp
        float other = __shfl_xor(acc, 8, 16); // on lane 0: imp
        if (lane16 == 0) {
            float2 sc = scale[s];
            float val = acc * sc.x + other * sc.y;
            push_rec(s, d, val, cnt, bins, ocnt, olist);
        }
    } else {
        int e = (b - ACT_BLOCKS) * 256 + threadIdx.x;
        int s = esrc[e];
        push_rec(s, edst[e], -brow[s], cnt, bins, ocnt, olist);
    }
}

// ------------------------------------------------- assemble: one block per row
__global__ __launch_bounds__(256) void row_assemble_k(
        const int* __restrict__ cnt,
        const int2* __restrict__ bins,
        float* __restrict__ out) {
    __shared__ float rowbuf[N_AGENTS];
    int r   = blockIdx.x;
    int tid = threadIdx.x;

    float4* rb4 = (float4*)rowbuf;
    float4 z = make_float4(0.f, 0.f, 0.f, 0.f);
    #pragma unroll
    for (int i = 0; i < 8; ++i)                   // 2048 float4 / 256 threads
        rb4[tid + i * 256] = z;
    __syncthreads();

    int c = cnt[r];
    c = c < CAP ? c : CAP;
    for (int i = tid; i < c; i += 256) {
        int2 rec = bins[(size_t)r * CAP + i];
        atomicAdd(&rowbuf[rec.x], __int_as_float(rec.y));
    }
    __syncthreads();

    float4* dst = (float4*)(out + (size_t)r * N_AGENTS);
    #pragma unroll
    for (int i = 0; i < 8; ++i)
        dst[tid + i * 256] = rb4[tid + i * 256];
}

// ------------------------------------------------- overflow fixup (normally empty)
__global__ __launch_bounds__(256) void overflow_k(
        const int* __restrict__ ocnt,
        const int4* __restrict__ olist,
        float* __restrict__ out) {
    int n = *ocnt;
    n = n < OVERCAP ? n : OVERCAP;
    for (int i = threadIdx.x; i < n; i += 256) {
        int4 rec = olist[i];
        atomicAdd(out + (size_t)rec.x * N_AGENTS + rec.y, __int_as_float(rec.z));
    }
}

// ---------------------------------------------------------------- launcher
extern "C" void kernel_launch(void* const* d_in, const int* in_sizes, int n_in,
                              void* d_out, int out_size, void* d_ws, size_t ws_size,
                              hipStream_t stream) {
    const float* feature      = (const float*)d_in[0];
    const float* next_feature = (const float*)d_in[1];
    const float* persona      = (const float*)d_in[2];
    const float* alpha        = (const float*)d_in[3];
    const float* beta         = (const float*)d_in[4];
    const float* gamma        = (const float*)d_in[5];
    const int*   act_src      = (const int*)d_in[6];
    const int*   act_dst      = (const int*)d_in[7];
    const int*   edge_src     = (const int*)d_in[8];
    const int*   edge_dst     = (const int*)d_in[9];

    float* out = (float*)d_out;

    // ws layout:
    //   T     : N*256 half           = 4 MiB
    //   scale : N float2             = 64 KiB
    //   brow  : N float              = 32 KiB
    //   cnt   : N int                = 32 KiB
    //   bins  : N*CAP int2           = 16 MiB
    //   ocnt  : 1 int (+ pad to 16B)
    //   olist : OVERCAP int4         = 64 KiB
    char* ws = (char*)d_ws;
    __half* T     = (__half*)ws;                 ws += (size_t)N_AGENTS * 256 * sizeof(__half);
    float2* scale = (float2*)ws;                 ws += (size_t)N_AGENTS * sizeof(float2);
    float*  brow  = (float*)ws;                  ws += (size_t)N_AGENTS * sizeof(float);
    int*    cnt   = (int*)ws;                    ws += (size_t)N_AGENTS * sizeof(int);
    int2*   bins  = (int2*)ws;                   ws += (size_t)N_AGENTS * CAP * sizeof(int2);
    int*    ocnt  = (int*)ws;                    ws += 16;
    int4*   olist = (int4*)ws;

    // 1) per-row precompute + counter zeroing
    row_prep_k<<<N_AGENTS / 4, 256, 0, stream>>>(
        feature, next_feature, persona, alpha, beta, gamma,
        (__half2*)T, scale, brow, cnt, ocnt);

    // 2) per-edge values + bin by source row (both edge lists in one dispatch)
    edge_bin_k<<<ACT_BLOCKS + COST_BLOCKS, 256, 0, stream>>>(
        act_src, act_dst, edge_src, edge_dst,
        T, scale, brow, cnt, bins, ocnt, olist);

    // 3) assemble rows in LDS, single coalesced write of the output
    row_assemble_k<<<N_AGENTS, 256, 0, stream>>>(cnt, bins, out);

    // 4) overflow fixup (no-op for this input; kept for robustness)
    overflow_k<<<1, 256, 0, stream>>>(ocnt, olist, out);
}

// Round 5
// 336.727 us; speedup vs baseline: 1.1944x; 1.0067x over previous
//
#include <hip/hip_runtime.h>
#include <hip/hip_fp16.h>

#define N_AGENTS 8192
#define FDIM 128
#define PDIM 16
#define NEDGES 262144
#define CAP 128          // per-row bin capacity; degree ~ Poisson(64), max ~105 << 128
#define OVERCAP 4096     // safety overflow list

typedef float floatx4 __attribute__((ext_vector_type(4)));   // native vecs for nontemporal
typedef int   intx2   __attribute__((ext_vector_type(2)));

// ------------------------------------------------- per-row precompute (1 wave/row)
// T[row][0:128)  = fp16 row-L2-normalized next_feature
// T[row][128:256)= fp16 (feature - next_feature)
// scale[row] = (persona.alpha, persona.gamma/F)   brow[row] = persona.beta
// Also zeroes cnt[row] and (block 0) the overflow counter.
__global__ __launch_bounds__(256) void row_prep_k(
        const float* __restrict__ feature,
        const float* __restrict__ next_feature,
        const float* __restrict__ persona,
        const float* __restrict__ alpha,
        const float* __restrict__ beta,
        const float* __restrict__ gamma,
        __half2* __restrict__ T2,
        float2* __restrict__ scale,
        float* __restrict__ brow,
        int* __restrict__ cnt,
        int* __restrict__ ocnt) {
    int row  = (blockIdx.x * blockDim.x + threadIdx.x) >> 6;   // one wave64 per row
    int lane = threadIdx.x & 63;
    if (blockIdx.x == 0 && threadIdx.x == 0) *ocnt = 0;
    if (row >= N_AGENTS) return;

    const float2* f2 = (const float2*)(feature      + (size_t)row * FDIM);
    const float2* n2 = (const float2*)(next_feature + (size_t)row * FDIM);
    float2 f  = f2[lane];
    float2 nx = n2[lane];

    float2 d = make_float2(f.x - nx.x, f.y - nx.y);
    float ss = nx.x * nx.x + nx.y * nx.y;

    float pa = 0.f, pb = 0.f, pg = 0.f;
    if (lane < PDIM) {
        float p = persona[(size_t)row * PDIM + lane];
        pa = p * alpha[lane];
        pb = p * beta[lane];
        pg = p * gamma[lane];
    }

    #pragma unroll
    for (int off = 32; off > 0; off >>= 1) {
        ss += __shfl_xor(ss, off);
        pa += __shfl_xor(pa, off);
        pb += __shfl_xor(pb, off);
        pg += __shfl_xor(pg, off);
    }

    float inv = 1.0f / sqrtf(ss);
    __half2* trow = T2 + (size_t)row * 128;
    trow[lane]      = __float22half2_rn(make_float2(nx.x * inv, nx.y * inv)); // nf
    trow[64 + lane] = __float22half2_rn(d);                                   // diff

    if (lane == 0) {
        scale[row] = make_float2(pa, pg * (1.0f / FDIM));
        brow[row]  = pb;
        cnt[row]   = 0;
    }
}

// 8 halves (one float4 chunk) fp16 dot, fp32 accumulate
__device__ inline float dot8(float4 a, float4 b) {
    const __half2* ha = (const __half2*)&a;
    const __half2* hb = (const __half2*)&b;
    float s = 0.f;
    #pragma unroll
    for (int j = 0; j < 4; ++j) {
        float2 fa = __half22float2(ha[j]);
        float2 fb = __half22float2(hb[j]);
        s += fa.x * fb.x + fa.y * fb.y;
    }
    return s;
}

// nontemporal push: bins are written once here, read once in row_assemble —
// keep them OUT of L2 so the 4 MiB T gather table stays resident.
__device__ inline void push_rec(int s, int d, float val,
                                int* cnt, intx2* bins,
                                int* ocnt, int4* olist) {
    int pos = atomicAdd(&cnt[s], 1);
    if (pos < CAP) {
        intx2 rec;
        rec.x = d;
        rec.y = __float_as_int(val);
        __builtin_nontemporal_store(rec, &bins[(size_t)s * CAP + pos]);
    } else {
        int op = atomicAdd(ocnt, 1);
        if (op < OVERCAP) olist[op] = make_int4(s, d, __float_as_int(val), 0);
    }
}

// ------------------------------------------------- edge values -> binned records
// blocks [0, ACT_BLOCKS): act edges, 16 lanes/edge (fp16 dots)
// blocks [ACT_BLOCKS, +COST_BLOCKS): cost edges, 1 thread/edge
#define ACT_BLOCKS ((NEDGES * 16) / 256)
#define COST_BLOCKS (NEDGES / 256)
__global__ __launch_bounds__(256) void edge_bin_k(
        const int* __restrict__ asrc,
        const int* __restrict__ adst,
        const int* __restrict__ esrc,
        const int* __restrict__ edst,
        const __half* __restrict__ T,
        const float2* __restrict__ scale,
        const float* __restrict__ brow,
        int* __restrict__ cnt,
        intx2* __restrict__ bins,
        int* __restrict__ ocnt,
        int4* __restrict__ olist) {
    int b = blockIdx.x;
    if (b < ACT_BLOCKS) {
        int gid    = b * 256 + threadIdx.x;
        int e      = gid >> 4;
        int lane16 = gid & 15;
        int s = asrc[e];
        int d = adst[e];
        const float4* ts = (const float4*)(T + (size_t)s * 256);
        const float4* td = (const float4*)(T + (size_t)d * 256);
        int i0 = lane16 * 2;          // lanes 0-7: nf chunks 0..15 ; lanes 8-15: diff 16..31
        float acc = dot8(ts[i0], td[i0]) + dot8(ts[i0 + 1], td[i0 + 1]);
        acc += __shfl_xor(acc, 1, 16);
        acc += __shfl_xor(acc, 2, 16);
        acc += __shfl_xor(acc, 4, 16);        // lanes 0-7 = sim, 8-15 = imp
        float other = __shfl_xor(acc, 8, 16); // on lane 0: imp
        if (lane16 == 0) {
            float2 sc = scale[s];
            float val = acc * sc.x + other * sc.y;
            push_rec(s, d, val, cnt, bins, ocnt, olist);
        }
    } else {
        int e = (b - ACT_BLOCKS) * 256 + threadIdx.x;
        int s = esrc[e];
        push_rec(s, edst[e], -brow[s], cnt, bins, ocnt, olist);
    }
}

// ------------------------------------------------- assemble: one block per row
__global__ __launch_bounds__(256) void row_assemble_k(
        const int* __restrict__ cnt,
        const intx2* __restrict__ bins,
        float* __restrict__ out) {
    __shared__ float rowbuf[N_AGENTS];
    int r   = blockIdx.x;
    int tid = threadIdx.x;

    floatx4* rb4 = (floatx4*)rowbuf;
    floatx4 z = (floatx4)0.f;
    #pragma unroll
    for (int i = 0; i < 8; ++i)                   // 2048 float4 / 256 threads
        rb4[tid + i * 256] = z;
    __syncthreads();

    int c = cnt[r];
    c = c < CAP ? c : CAP;
    for (int i = tid; i < c; i += 256) {
        intx2 rec = bins[(size_t)r * CAP + i];
        atomicAdd(&rowbuf[rec.x], __int_as_float(rec.y));
    }
    __syncthreads();

    // output is written once and never re-read: stream past L2
    floatx4* dst = (floatx4*)(out + (size_t)r * N_AGENTS);
    #pragma unroll
    for (int i = 0; i < 8; ++i)
        __builtin_nontemporal_store(rb4[tid + i * 256], &dst[tid + i * 256]);
}

// ------------------------------------------------- overflow fixup (normally empty)
__global__ __launch_bounds__(256) void overflow_k(
        const int* __restrict__ ocnt,
        const int4* __restrict__ olist,
        float* __restrict__ out) {
    int n = *ocnt;
    n = n < OVERCAP ? n : OVERCAP;
    for (int i = threadIdx.x; i < n; i += 256) {
        int4 rec = olist[i];
        atomicAdd(out + (size_t)rec.x * N_AGENTS + rec.y, __int_as_float(rec.z));
    }
}

// ---------------------------------------------------------------- launcher
extern "C" void kernel_launch(void* const* d_in, const int* in_sizes, int n_in,
                              void* d_out, int out_size, void* d_ws, size_t ws_size,
                              hipStream_t stream) {
    const float* feature      = (const float*)d_in[0];
    const float* next_feature = (const float*)d_in[1];
    const float* persona      = (const float*)d_in[2];
    const float* alpha        = (const float*)d_in[3];
    const float* beta         = (const float*)d_in[4];
    const float* gamma        = (const float*)d_in[5];
    const int*   act_src      = (const int*)d_in[6];
    const int*   act_dst      = (const int*)d_in[7];
    const int*   edge_src     = (const int*)d_in[8];
    const int*   edge_dst     = (const int*)d_in[9];

    float* out = (float*)d_out;

    // ws layout:
    //   T     : N*256 half           = 4 MiB
    //   scale : N float2             = 64 KiB
    //   brow  : N float              = 32 KiB
    //   cnt   : N int                = 32 KiB
    //   bins  : N*CAP intx2          = 8 MiB
    //   ocnt  : 1 int (pad 16B)
    //   olist : OVERCAP int4         = 64 KiB
    char* ws = (char*)d_ws;
    __half* T     = (__half*)ws;                 ws += (size_t)N_AGENTS * 256 * sizeof(__half);
    float2* scale = (float2*)ws;                 ws += (size_t)N_AGENTS * sizeof(float2);
    float*  brow  = (float*)ws;                  ws += (size_t)N_AGENTS * sizeof(float);
    int*    cnt   = (int*)ws;                    ws += (size_t)N_AGENTS * sizeof(int);
    intx2*  bins  = (intx2*)ws;                  ws += (size_t)N_AGENTS * CAP * sizeof(intx2);
    int*    ocnt  = (int*)ws;                    ws += 16;
    int4*   olist = (int4*)ws;

    // 1) per-row precompute + counter zeroing
    row_prep_k<<<N_AGENTS / 4, 256, 0, stream>>>(
        feature, next_feature, persona, alpha, beta, gamma,
        (__half2*)T, scale, brow, cnt, ocnt);

    // 2) per-edge values + bin by source row (both edge lists in one dispatch)
    edge_bin_k<<<ACT_BLOCKS + COST_BLOCKS, 256, 0, stream>>>(
        act_src, act_dst, edge_src, edge_dst,
        T, scale, brow, cnt, bins, ocnt, olist);

    // 3) assemble rows in LDS, single coalesced NT write of the output
    row_assemble_k<<<N_AGENTS, 256, 0, stream>>>(cnt, bins, out);

    // 4) overflow fixup (no-op for this input; kept for robustness)
    overflow_k<<<1, 256, 0, stream>>>(ocnt, olist, out);
}